// Round 1
// baseline (13455.664 us; speedup 1.0000x reference)
//
#include <hip/hip_runtime.h>

constexpr int kNB = 2, kNS = 2, kNF = 512, kNPTS = 1024;
constexpr int kNLS = 12, kNLV = 6, kH = 64, kF = 29, kNOUT = 24;
constexpr int kNTGT = kNB * kNF;  // 1024
constexpr float kEPS = 1e-8f;

// LDS float offsets for staged weights
constexpr int OW1 = 0;
constexpr int OB1 = OW1 + kF * kH;     // 1856
constexpr int OW2 = OB1 + kH;          // 1920
constexpr int OB2 = OW2 + kH * kH;     // 6016
constexpr int OW3 = OB2 + kH;          // 6080
constexpr int OB3 = OW3 + kH * kH;     // 10176
constexpr int OWO = OB3 + kH;          // 10240
constexpr int OBO = OWO + kH * kNOUT;  // 11776
constexpr int WTOT = OBO + kNOUT;      // 11800 floats = 46.1 KB

__device__ __forceinline__ float wred64(float v) {
#pragma unroll
  for (int off = 32; off > 0; off >>= 1) v += __shfl_xor(v, off, 64);
  return v;
}

// h = silu(x @ W + b), W is (K,N) row-major in LDS, broadcast reads.
template <int K, int N>
__device__ __forceinline__ void dense_silu(const float* __restrict__ x,
                                           const float* __restrict__ W,
                                           const float* __restrict__ bias,
                                           float* __restrict__ h) {
#pragma unroll
  for (int j0 = 0; j0 < N; j0 += 8) {
    float a[8];
#pragma unroll
    for (int u = 0; u < 8; ++u) a[u] = bias[j0 + u];
#pragma unroll
    for (int i = 0; i < K; ++i) {
      const float xi = x[i];
#pragma unroll
      for (int u = 0; u < 8; ++u) a[u] = fmaf(xi, W[i * N + j0 + u], a[u]);
    }
#pragma unroll
    for (int u = 0; u < 8; ++u) {
      const float t = a[u];
      h[j0 + u] = t / (1.0f + __expf(-t));
    }
  }
}

__device__ __forceinline__ void copy_f(float* dst, const float* src, int n,
                                       int tid, int nthr) {
  for (int i = tid; i < n; i += nthr) dst[i] = src[i];
}

__global__ void prep_kernel(const float* __restrict__ normals,
                            float* __restrict__ nrm) {
  const int i = blockIdx.x * blockDim.x + threadIdx.x;
  if (i < kNTGT) {
    const float x = normals[i * 3 + 0];
    const float y = normals[i * 3 + 1];
    const float z = normals[i * 3 + 2];
    const float inv = rsqrtf(x * x + y * y + z * z);
    nrm[i * 3 + 0] = x * inv;
    nrm[i * 3 + 1] = y * inv;
    nrm[i * 3 + 2] = z * inv;
  }
}

// One block per target (all_pos index t in [0,1024)); 512 threads = 512 sources.
template <bool FIRST>
__global__ void interact_kernel(
    const float* __restrict__ centroids, const float* __restrict__ nrm,
    const float* __restrict__ areas, const float* __restrict__ refl,
    const float* __restrict__ cW1, const float* __restrict__ cb1,
    const float* __restrict__ cW2, const float* __restrict__ cb2,
    const float* __restrict__ cW3, const float* __restrict__ cb3,
    const float* __restrict__ cWo, const float* __restrict__ cbo, int layer,
    const float* __restrict__ scal_in, const float* __restrict__ vecs_in,
    float* __restrict__ scal_out, float* __restrict__ vecs_out) {
  __shared__ float wbuf[WTOT];
  __shared__ float red[8 * 32];
  const int t = blockIdx.x;
  const int tid = threadIdx.x;
  const float tx = centroids[t * 3 + 0];
  const float ty = centroids[t * 3 + 1];
  const float tz = centroids[t * 3 + 2];

  float accS[kNLS];
  float accV[kNLV * 3];
#pragma unroll
  for (int k = 0; k < kNLS; ++k) accS[k] = 0.f;
#pragma unroll
  for (int k = 0; k < kNLV * 3; ++k) accV[k] = 0.f;

  const int src = tid;  // blockDim.x == kNF

  for (int b = 0; b < kNB; ++b) {
    const int sg = b * kNF + src;
    const float px = centroids[sg * 3 + 0];
    const float py = centroids[sg * 3 + 1];
    const float pz = centroids[sg * 3 + 2];
    const float nx = nrm[sg * 3 + 0];
    const float ny = nrm[sg * 3 + 1];
    const float nz = nrm[sg * 3 + 2];
    const float ws_ = areas[sg];
    const float rvx = tx - px, rvy = ty - py, rvz = tz - pz;
    const float r = sqrtf(rvx * rvx + rvy * rvy + rvz * rvz + kEPS * kEPS);
    const float rinv = 1.0f / r;
    const float rhx = rvx * rinv, rhy = rvy * rinv, rhz = rvz * rinv;
    const float c = rhx * nx + rhy * ny + rhz * nz;
    float x[kF];
    x[1] = 1.0f;
    x[2] = c;
    x[3] = 0.5f * (3.0f * c * c - 1.0f);
    x[4] = 0.5f * (5.0f * c * c * c - 3.0f * c);
    if (FIRST) {
#pragma unroll
      for (int k = 5; k < kF; ++k) x[k] = 0.f;
    } else {
#pragma unroll
      for (int k = 0; k < kNLS; ++k) x[5 + k] = scal_in[sg * kNLS + k];
#pragma unroll
      for (int v = 0; v < kNLV; ++v) {
        const float vx = vecs_in[sg * 18 + v * 3 + 0];
        const float vy = vecs_in[sg * 18 + v * 3 + 1];
        const float vz = vecs_in[sg * 18 + v * 3 + 2];
        x[17 + v] = rhx * vx + rhy * vy + rhz * vz;
        x[23 + v] = nx * vx + ny * vy + nz * vz;
      }
    }
    for (int s = 0; s < kNS; ++s) {
      x[0] = __logf(r / refl[s]);
      __syncthreads();  // protect previous combo's weights
      const int widx = (layer * kNB + b) * kNS + s;
      copy_f(wbuf + OW1, cW1 + widx * (kF * kH), kF * kH, tid, 512);
      copy_f(wbuf + OB1, cb1 + widx * kH, kH, tid, 512);
      copy_f(wbuf + OW2, cW2 + widx * (kH * kH), kH * kH, tid, 512);
      copy_f(wbuf + OB2, cb2 + widx * kH, kH, tid, 512);
      copy_f(wbuf + OW3, cW3 + widx * (kH * kH), kH * kH, tid, 512);
      copy_f(wbuf + OB3, cb3 + widx * kH, kH, tid, 512);
      copy_f(wbuf + OWO, cWo + widx * (kH * kNOUT), kH * kNOUT, tid, 512);
      copy_f(wbuf + OBO, cbo + widx * kNOUT, kNOUT, tid, 512);
      __syncthreads();
      float h1[kH], h2[kH];
      dense_silu<kF, kH>(x, wbuf + OW1, wbuf + OB1, h1);
      dense_silu<kH, kH>(h1, wbuf + OW2, wbuf + OB2, h2);
      dense_silu<kH, kH>(h2, wbuf + OW3, wbuf + OB3, h1);  // h3 -> h1
      // output layer fused with moment accumulation
#pragma unroll
      for (int j0 = 0; j0 < kNOUT; j0 += 8) {
        float a[8];
#pragma unroll
        for (int u = 0; u < 8; ++u) a[u] = wbuf[OBO + j0 + u];
#pragma unroll
        for (int i = 0; i < kH; ++i) {
          const float hi = h1[i];
#pragma unroll
          for (int u = 0; u < 8; ++u)
            a[u] = fmaf(hi, wbuf[OWO + i * kNOUT + j0 + u], a[u]);
        }
#pragma unroll
        for (int u = 0; u < 8; ++u) {
          const int j = j0 + u;
          const float val = a[u] * ws_;
          if (j < kNLS) {
            accS[j] += val;
          } else if (j < kNLS + kNLV) {
            const int v = j - kNLS;
            accV[v * 3 + 0] += val * rhx;
            accV[v * 3 + 1] += val * rhy;
            accV[v * 3 + 2] += val * rhz;
          } else {
            const int v = j - kNLS - kNLV;
            accV[v * 3 + 0] += val * nx;
            accV[v * 3 + 1] += val * ny;
            accV[v * 3 + 2] += val * nz;
          }
        }
      }
    }
  }
  // block reduction: 30 values over 512 threads
#pragma unroll
  for (int k = 0; k < kNLS; ++k) accS[k] = wred64(accS[k]);
#pragma unroll
  for (int k = 0; k < kNLV * 3; ++k) accV[k] = wred64(accV[k]);
  const int wid = tid >> 6, lane = tid & 63;
  __syncthreads();  // wbuf/red reuse safety
  if (lane == 0) {
#pragma unroll
    for (int k = 0; k < kNLS; ++k) red[wid * 32 + k] = accS[k];
#pragma unroll
    for (int k = 0; k < kNLV * 3; ++k) red[wid * 32 + kNLS + k] = accV[k];
  }
  __syncthreads();
  if (tid < 30) {
    float sum = 0.f;
#pragma unroll
    for (int w = 0; w < 8; ++w) sum += red[w * 32 + tid];
    if (tid < kNLS)
      scal_out[t * kNLS + tid] = sum;
    else
      vecs_out[t * 18 + (tid - kNLS)] = sum;
  }
}

__global__ void final_kernel(
    const float* __restrict__ pred, const float* __restrict__ centroids,
    const float* __restrict__ nrm, const float* __restrict__ areas,
    const float* __restrict__ refl, const float* __restrict__ fW1,
    const float* __restrict__ fb1, const float* __restrict__ fW2,
    const float* __restrict__ fb2, const float* __restrict__ fW3,
    const float* __restrict__ fb3, const float* __restrict__ fWo,
    const float* __restrict__ fbo, const float* __restrict__ scal_in,
    const float* __restrict__ vecs_in, const float* __restrict__ calib,
    float* __restrict__ out) {
  __shared__ float wbuf[WTOT];
  __shared__ float red[8 * 4];
  const int t = blockIdx.x;
  const int tid = threadIdx.x;
  const float tx = pred[t * 3 + 0];
  const float ty = pred[t * 3 + 1];
  const float tz = pred[t * 3 + 2];
  float accP = 0.f, accVx = 0.f, accVy = 0.f, accVz = 0.f;
  const int src = tid;
  for (int b = 0; b < kNB; ++b) {
    const int sg = b * kNF + src;
    const float px = centroids[sg * 3 + 0];
    const float py = centroids[sg * 3 + 1];
    const float pz = centroids[sg * 3 + 2];
    const float nx = nrm[sg * 3 + 0];
    const float ny = nrm[sg * 3 + 1];
    const float nz = nrm[sg * 3 + 2];
    const float ws_ = areas[sg];
    const float rvx = tx - px, rvy = ty - py, rvz = tz - pz;
    const float r = sqrtf(rvx * rvx + rvy * rvy + rvz * rvz + kEPS * kEPS);
    const float rinv = 1.0f / r;
    const float rhx = rvx * rinv, rhy = rvy * rinv, rhz = rvz * rinv;
    const float c = rhx * nx + rhy * ny + rhz * nz;
    float x[kF];
    x[1] = 1.0f;
    x[2] = c;
    x[3] = 0.5f * (3.0f * c * c - 1.0f);
    x[4] = 0.5f * (5.0f * c * c * c - 3.0f * c);
#pragma unroll
    for (int k = 0; k < kNLS; ++k) x[5 + k] = scal_in[sg * kNLS + k];
#pragma unroll
    for (int v = 0; v < kNLV; ++v) {
      const float vx = vecs_in[sg * 18 + v * 3 + 0];
      const float vy = vecs_in[sg * 18 + v * 3 + 1];
      const float vz = vecs_in[sg * 18 + v * 3 + 2];
      x[17 + v] = rhx * vx + rhy * vy + rhz * vz;
      x[23 + v] = nx * vx + ny * vy + nz * vz;
    }
    for (int s = 0; s < kNS; ++s) {
      x[0] = __logf(r / refl[s]);
      __syncthreads();
      const int widx = b * kNS + s;
      copy_f(wbuf + OW1, fW1 + widx * (kF * kH), kF * kH, tid, 512);
      copy_f(wbuf + OB1, fb1 + widx * kH, kH, tid, 512);
      copy_f(wbuf + OW2, fW2 + widx * (kH * kH), kH * kH, tid, 512);
      copy_f(wbuf + OB2, fb2 + widx * kH, kH, tid, 512);
      copy_f(wbuf + OW3, fW3 + widx * (kH * kH), kH * kH, tid, 512);
      copy_f(wbuf + OB3, fb3 + widx * kH, kH, tid, 512);
      copy_f(wbuf + OWO, fWo + widx * (kH * 3), kH * 3, tid, 512);
      copy_f(wbuf + OBO, fbo + widx * 3, 3, tid, 512);
      __syncthreads();
      float h1[kH], h2[kH];
      dense_silu<kF, kH>(x, wbuf + OW1, wbuf + OB1, h1);
      dense_silu<kH, kH>(h1, wbuf + OW2, wbuf + OB2, h2);
      dense_silu<kH, kH>(h2, wbuf + OW3, wbuf + OB3, h1);
      float a0 = wbuf[OBO + 0], a1 = wbuf[OBO + 1], a2 = wbuf[OBO + 2];
#pragma unroll
      for (int i = 0; i < kH; ++i) {
        const float hi = h1[i];
        a0 = fmaf(hi, wbuf[OWO + i * 3 + 0], a0);
        a1 = fmaf(hi, wbuf[OWO + i * 3 + 1], a1);
        a2 = fmaf(hi, wbuf[OWO + i * 3 + 2], a2);
      }
      accP += a0 * ws_;
      accVx += ws_ * (a1 * rhx + a2 * nx);
      accVy += ws_ * (a1 * rhy + a2 * ny);
      accVz += ws_ * (a1 * rhz + a2 * nz);
    }
  }
  accP = wred64(accP);
  accVx = wred64(accVx);
  accVy = wred64(accVy);
  accVz = wred64(accVz);
  const int wid = tid >> 6, lane = tid & 63;
  __syncthreads();
  if (lane == 0) {
    red[wid * 4 + 0] = accP;
    red[wid * 4 + 1] = accVx;
    red[wid * 4 + 2] = accVy;
    red[wid * 4 + 3] = accVz;
  }
  __syncthreads();
  if (tid < 4) {
    float sum = 0.f;
#pragma unroll
    for (int w = 0; w < 8; ++w) sum += red[w * 4 + tid];
    const float o = (tid == 0) ? (calib[0] * sum + calib[1]) : (calib[2] * sum);
    out[t * 4 + tid] = o;
  }
}

extern "C" void kernel_launch(void* const* d_in, const int* in_sizes, int n_in,
                              void* d_out, int out_size, void* d_ws,
                              size_t ws_size, hipStream_t stream) {
  const float* pred = (const float*)d_in[0];
  const float* cent = (const float*)d_in[1];
  const float* normals = (const float*)d_in[2];
  const float* areas = (const float*)d_in[3];
  const float* refl = (const float*)d_in[4];
  const float* cW1 = (const float*)d_in[5];
  const float* cb1 = (const float*)d_in[6];
  const float* cW2 = (const float*)d_in[7];
  const float* cb2 = (const float*)d_in[8];
  const float* cW3 = (const float*)d_in[9];
  const float* cb3 = (const float*)d_in[10];
  const float* cWo = (const float*)d_in[11];
  const float* cbo = (const float*)d_in[12];
  const float* fW1 = (const float*)d_in[13];
  const float* fb1 = (const float*)d_in[14];
  const float* fW2 = (const float*)d_in[15];
  const float* fb2 = (const float*)d_in[16];
  const float* fW3 = (const float*)d_in[17];
  const float* fb3 = (const float*)d_in[18];
  const float* fWo = (const float*)d_in[19];
  const float* fbo = (const float*)d_in[20];
  const float* calib = (const float*)d_in[21];

  float* ws = (float*)d_ws;
  float* nrm = ws;                       // 3072
  float* scalA = nrm + kNTGT * 3;        // 12288
  float* vecsA = scalA + kNTGT * kNLS;   // 18432
  float* scalB = vecsA + kNTGT * kNLV * 3;
  float* vecsB = scalB + kNTGT * kNLS;
  float* outp = (float*)d_out;

  prep_kernel<<<(kNTGT + 255) / 256, 256, 0, stream>>>(normals, nrm);
  interact_kernel<true><<<kNTGT, 512, 0, stream>>>(
      cent, nrm, areas, refl, cW1, cb1, cW2, cb2, cW3, cb3, cWo, cbo, 0,
      nullptr, nullptr, scalA, vecsA);
  interact_kernel<false><<<kNTGT, 512, 0, stream>>>(
      cent, nrm, areas, refl, cW1, cb1, cW2, cb2, cW3, cb3, cWo, cbo, 1, scalA,
      vecsA, scalB, vecsB);
  final_kernel<<<kNPTS, 512, 0, stream>>>(pred, cent, nrm, areas, refl, fW1,
                                          fb1, fW2, fb2, fW3, fb3, fWo, fbo,
                                          scalB, vecsB, calib, outp);
}